// Round 2
// baseline (573.198 us; speedup 1.0000x reference)
//
#include <hip/hip_runtime.h>

typedef __bf16 bf16_t;
typedef __bf16 bf16x8 __attribute__((ext_vector_type(8)));
typedef __bf16 bf16x4 __attribute__((ext_vector_type(4)));
typedef float  f32x4  __attribute__((ext_vector_type(4)));

#define T_STEPS 512
#define BATCH   2048
#define NS      64
#define HID     32
#define HSTR    40   // bf16 elems per LDS h row: rows 16B-aligned, 2-way bank alias max (free)
#define FSTR    36   // f32 elems per LDS final-h row

__device__ __forceinline__ float fast_sigmoid(float x) {
  return __builtin_amdgcn_rcpf(1.0f + __builtin_amdgcn_exp2f(-1.4426950408889634f * x));
}
__device__ __forceinline__ float fast_tanh(float x) {
  return 1.0f - 2.0f * __builtin_amdgcn_rcpf(1.0f + __builtin_amdgcn_exp2f(2.8853900817779268f * x));
}

// lgkm-only barrier: keeps global x-prefetch loads in flight across the step barrier
__device__ __forceinline__ void barrier_lgkm() {
  asm volatile("s_waitcnt lgkmcnt(0)\n\ts_barrier" ::: "memory");
}

__global__ __launch_bounds__(128)
void lstm_policy_kernel(const float* __restrict__ x,
                        const float* __restrict__ W_ih,
                        const float* __restrict__ W_hh,
                        const float* __restrict__ b_ih,
                        const float* __restrict__ b_hh,
                        const float* __restrict__ W_d,
                        const float* __restrict__ b_d,
                        float* __restrict__ out)
{
  __shared__ bf16_t hbuf[2][16 * HSTR];   // double-buffered h (bf16), [row][unit]
  __shared__ float  hf[16 * FSTR];        // final relu(h) f32 for dense epilogue

  const int tid  = threadIdx.x;
  const int wave = tid >> 6;              // 0..1 : unit-tile
  const int lane = tid & 63;
  const int m    = lane & 15;             // batch row within tile
  const int q    = lane >> 4;             // 0..3
  const int u0   = wave << 4;             // unit base for this wave's gate tiles
  const int row0 = blockIdx.x << 4;       // global batch row base

  // zero h_{-1}
  for (int i = tid; i < 16 * HSTR; i += 128) hbuf[0][i] = (bf16_t)0.0f;

  // ---- preload + convert weight A-frags (A[m=unit_local][k], lane: unit=m, k=q*8+j) ----
  bf16x8 a_ih[4][2], a_hh[4];
  f32x4  bias[4];
  #pragma unroll
  for (int G = 0; G < 4; ++G) {
    const int wrow = (G << 5) + u0 + m;     // row of W_ih/W_hh (gate-major, 4H=128 rows)
    const float* pih = W_ih + wrow * 64;
    const float* phh = W_hh + (wrow << 5);
    #pragma unroll
    for (int j = 0; j < 8; ++j) {
      a_ih[G][0][j] = (bf16_t)pih[(q << 3) + j];
      a_ih[G][1][j] = (bf16_t)pih[32 + (q << 3) + j];
      a_hh[G][j]    = (bf16_t)phh[(q << 3) + j];
    }
    #pragma unroll
    for (int r = 0; r < 4; ++r) {
      const int u = (G << 5) + u0 + (q << 2) + r;  // C-cell gate-row for acc reg r
      bias[G][r] = b_ih[u] + b_hh[u];
    }
  }

  // ---- x prefetch (distance 2, fp32 in registers): lane needs feats q*8..+7 and 32+q*8..+7 of row m ----
  const size_t xstep = (size_t)BATCH * NS;
  const float* xr = x + (size_t)(row0 + m) * NS + (q << 3);
  f32x4 xf[2][4];
  xf[0][0] = *(const f32x4*)(xr);
  xf[0][1] = *(const f32x4*)(xr + 4);
  xf[0][2] = *(const f32x4*)(xr + 32);
  xf[0][3] = *(const f32x4*)(xr + 36);
  xf[1][0] = *(const f32x4*)(xr + xstep);
  xf[1][1] = *(const f32x4*)(xr + xstep + 4);
  xf[1][2] = *(const f32x4*)(xr + xstep + 32);
  xf[1][3] = *(const f32x4*)(xr + xstep + 36);

  float cst[4] = {0.0f, 0.0f, 0.0f, 0.0f};  // c-state: units u0+4q+r, row m — lane-resident

  __syncthreads();

  #pragma unroll 2
  for (int t = 0; t < T_STEPS; ++t) {
    const int pb = t & 1;
    // convert this step's x floats -> bf16 B-frags (off the h-dependent path)
    bf16x8 xA, xB;
    #pragma unroll
    for (int j = 0; j < 4; ++j) {
      xA[j]     = (bf16_t)xf[pb][0][j];
      xA[4 + j] = (bf16_t)xf[pb][1][j];
      xB[j]     = (bf16_t)xf[pb][2][j];
      xB[4 + j] = (bf16_t)xf[pb][3][j];
    }
    // x-part MFMAs (independent of recurrence; bias rides in as C)
    f32x4 ai = __builtin_amdgcn_mfma_f32_16x16x32_bf16(a_ih[0][0], xA, bias[0], 0, 0, 0);
    f32x4 af = __builtin_amdgcn_mfma_f32_16x16x32_bf16(a_ih[1][0], xA, bias[1], 0, 0, 0);
    f32x4 ag = __builtin_amdgcn_mfma_f32_16x16x32_bf16(a_ih[2][0], xA, bias[2], 0, 0, 0);
    f32x4 ao = __builtin_amdgcn_mfma_f32_16x16x32_bf16(a_ih[3][0], xA, bias[3], 0, 0, 0);
    ai = __builtin_amdgcn_mfma_f32_16x16x32_bf16(a_ih[0][1], xB, ai, 0, 0, 0);
    af = __builtin_amdgcn_mfma_f32_16x16x32_bf16(a_ih[1][1], xB, af, 0, 0, 0);
    ag = __builtin_amdgcn_mfma_f32_16x16x32_bf16(a_ih[2][1], xB, ag, 0, 0, 0);
    ao = __builtin_amdgcn_mfma_f32_16x16x32_bf16(a_ih[3][1], xB, ao, 0, 0, 0);
    // prefetch x for t+2 (stays in flight across the lgkm-only barrier)
    {
      const float* pf = xr + (size_t)((t + 2 < T_STEPS) ? (t + 2) : t) * xstep;
      xf[pb][0] = *(const f32x4*)(pf);
      xf[pb][1] = *(const f32x4*)(pf + 4);
      xf[pb][2] = *(const f32x4*)(pf + 32);
      xf[pb][3] = *(const f32x4*)(pf + 36);
    }
    // dependent h-part: B[k=unit q*8+j][n=row m] from LDS (contiguous -> ds_read_b128)
    const bf16x8 hfr = *(const bf16x8*)(&hbuf[pb][m * HSTR + (q << 3)]);
    ai = __builtin_amdgcn_mfma_f32_16x16x32_bf16(a_hh[0], hfr, ai, 0, 0, 0);
    af = __builtin_amdgcn_mfma_f32_16x16x32_bf16(a_hh[1], hfr, af, 0, 0, 0);
    ag = __builtin_amdgcn_mfma_f32_16x16x32_bf16(a_hh[2], hfr, ag, 0, 0, 0);
    ao = __builtin_amdgcn_mfma_f32_16x16x32_bf16(a_hh[3], hfr, ao, 0, 0, 0);
    // elementwise: 4 cells/lane (units u0+4q+r, row m)
    bf16x4 hv;
    #pragma unroll
    for (int r = 0; r < 4; ++r) {
      const float ig = fast_sigmoid(ai[r]);
      const float fg = fast_sigmoid(af[r]);
      const float gg = fast_tanh(ag[r]);
      const float og = fast_sigmoid(ao[r]);
      const float cn = fg * cst[r] + ig * gg;
      cst[r] = cn;
      const float h = og * fast_tanh(cn);
      hv[r] = (bf16_t)h;
      if (t == T_STEPS - 1) hf[m * FSTR + u0 + (q << 2) + r] = fmaxf(h, 0.0f);
    }
    // contiguous 4-unit write -> ds_write_b64 (8B-aligned: 80m + 2u0 + 8q)
    *(bf16x4*)(&hbuf[pb ^ 1][m * HSTR + u0 + (q << 2)]) = hv;
    barrier_lgkm();
  }

  __syncthreads();

  // dense epilogue: out[row][a] = relu(h_T[row]) . W_d[a] + b_d[a]   (fp32 out)
  if (tid < 48) {
    const int r = tid / 3;
    const int a = tid - r * 3;
    float s = b_d[a];
    #pragma unroll
    for (int u = 0; u < HID; ++u)
      s += hf[r * FSTR + u] * W_d[a * HID + u];
    out[(size_t)(row0 + r) * 3 + a] = s;
  }
}

extern "C" void kernel_launch(void* const* d_in, const int* in_sizes, int n_in,
                              void* d_out, int out_size, void* d_ws, size_t ws_size,
                              hipStream_t stream) {
  const float* x    = (const float*)d_in[0];
  const float* W_ih = (const float*)d_in[1];
  const float* W_hh = (const float*)d_in[2];
  const float* b_ih = (const float*)d_in[3];
  const float* b_hh = (const float*)d_in[4];
  const float* W_d  = (const float*)d_in[5];
  const float* b_d  = (const float*)d_in[6];
  float* out = (float*)d_out;

  dim3 grid(BATCH / 16);   // 128 blocks x 16 batch rows
  dim3 block(128);         // 2 waves: unit-tiles [0,16) and [16,32)
  hipLaunchKernelGGL(lstm_policy_kernel, grid, block, 0, stream,
                     x, W_ih, W_hh, b_ih, b_hh, W_d, b_d, out);
}

// Round 3
// 540.233 us; speedup vs baseline: 1.0610x; 1.0610x over previous
//
#include <hip/hip_runtime.h>

typedef __bf16 bf16_t;
typedef __bf16 bf16x8 __attribute__((ext_vector_type(8)));
typedef __bf16 bf16x4 __attribute__((ext_vector_type(4)));
typedef float  f32x4  __attribute__((ext_vector_type(4)));

#define T_STEPS 512
#define BATCH   2048
#define NS      64
#define HID     32
#define HSTR    40   // bf16 elems per LDS h row: rows 16B-aligned, <=2-way bank alias (free)
#define FSTR    36   // f32 elems per LDS final-h row
#define PFD     4    // x prefetch depth (steps); in-flight ~4*step >> HBM latency

__device__ __forceinline__ float fast_sigmoid(float x) {
  return __builtin_amdgcn_rcpf(1.0f + __builtin_amdgcn_exp2f(-1.4426950408889634f * x));
}
__device__ __forceinline__ float fast_tanh(float x) {
  return 1.0f - 2.0f * __builtin_amdgcn_rcpf(1.0f + __builtin_amdgcn_exp2f(2.8853900817779268f * x));
}

// lgkm-only barrier: keeps global x-prefetch loads in flight across the step barrier
__device__ __forceinline__ void barrier_lgkm() {
  asm volatile("s_waitcnt lgkmcnt(0)\n\ts_barrier" ::: "memory");
}

__global__ __launch_bounds__(128, 1)
void lstm_policy_kernel(const float* __restrict__ x,
                        const float* __restrict__ W_ih,
                        const float* __restrict__ W_hh,
                        const float* __restrict__ b_ih,
                        const float* __restrict__ b_hh,
                        const float* __restrict__ W_d,
                        const float* __restrict__ b_d,
                        float* __restrict__ out)
{
  __shared__ bf16_t hbuf[2][16 * HSTR];   // double-buffered h (bf16), [row][unit]
  __shared__ float  hf[16 * FSTR];        // final relu(h) f32 for dense epilogue

  const int tid  = threadIdx.x;
  const int wave = tid >> 6;              // 0..1 : unit-tile
  const int lane = tid & 63;
  const int m    = lane & 15;             // batch row within tile
  const int q    = lane >> 4;             // 0..3
  const int u0   = wave << 4;             // unit base for this wave's gate tiles
  const int row0 = blockIdx.x << 4;       // global batch row base

  // zero h_{-1}
  for (int i = tid; i < 16 * HSTR; i += 128) hbuf[0][i] = (bf16_t)0.0f;

  // ---- preload + convert weight A-frags (A[m=unit_local][k], lane: unit=m, k=q*8+j) ----
  bf16x8 a_ih[4][2], a_hh[4];
  f32x4  bias[4];
  #pragma unroll
  for (int G = 0; G < 4; ++G) {
    const int wrow = (G << 5) + u0 + m;     // row of W_ih/W_hh (gate-major, 4H=128 rows)
    const float* pih = W_ih + wrow * 64;
    const float* phh = W_hh + (wrow << 5);
    #pragma unroll
    for (int j = 0; j < 8; ++j) {
      a_ih[G][0][j] = (bf16_t)pih[(q << 3) + j];
      a_ih[G][1][j] = (bf16_t)pih[32 + (q << 3) + j];
      a_hh[G][j]    = (bf16_t)phh[(q << 3) + j];
    }
    #pragma unroll
    for (int r = 0; r < 4; ++r) {
      const int u = (G << 5) + u0 + (q << 2) + r;  // C-cell gate-row for acc reg r
      bias[G][r] = b_ih[u] + b_hh[u];
    }
  }

  // ---- x prefetch ring (depth PFD, fp32 in registers) ----
  // lane needs feats q*8..+7 and 32+q*8..+7 of row m, for steps t..t+PFD-1
  const size_t xstep = (size_t)BATCH * NS;
  const float* xr = x + (size_t)(row0 + m) * NS + (q << 3);
  f32x4 xf[PFD][4];
  #pragma unroll
  for (int d = 0; d < PFD; ++d) {
    const float* p = xr + (size_t)d * xstep;
    xf[d][0] = *(const f32x4*)(p);
    xf[d][1] = *(const f32x4*)(p + 4);
    xf[d][2] = *(const f32x4*)(p + 32);
    xf[d][3] = *(const f32x4*)(p + 36);
  }

  float cst[4] = {0.0f, 0.0f, 0.0f, 0.0f};  // c-state: units u0+4q+r, row m — lane-resident

  __syncthreads();

  #pragma unroll PFD
  for (int t = 0; t < T_STEPS; ++t) {
    const int pb = t & 1;
    const int sl = t & (PFD - 1);           // prefetch ring slot (static after unroll)
    // convert this step's x floats -> bf16 B-frags (off the h-dependent path)
    bf16x8 xA, xB;
    #pragma unroll
    for (int j = 0; j < 4; ++j) {
      xA[j]     = (bf16_t)xf[sl][0][j];
      xA[4 + j] = (bf16_t)xf[sl][1][j];
      xB[j]     = (bf16_t)xf[sl][2][j];
      xB[4 + j] = (bf16_t)xf[sl][3][j];
    }
    // reload this slot for t+PFD (stays in flight across the lgkm-only barriers)
    {
      const int tp = (t + PFD < T_STEPS) ? (t + PFD) : t;
      const float* pf = xr + (size_t)tp * xstep;
      xf[sl][0] = *(const f32x4*)(pf);
      xf[sl][1] = *(const f32x4*)(pf + 4);
      xf[sl][2] = *(const f32x4*)(pf + 32);
      xf[sl][3] = *(const f32x4*)(pf + 36);
    }
    // x-part MFMAs (independent of recurrence; bias rides in as C)
    f32x4 ai = __builtin_amdgcn_mfma_f32_16x16x32_bf16(a_ih[0][0], xA, bias[0], 0, 0, 0);
    f32x4 af = __builtin_amdgcn_mfma_f32_16x16x32_bf16(a_ih[1][0], xA, bias[1], 0, 0, 0);
    f32x4 ag = __builtin_amdgcn_mfma_f32_16x16x32_bf16(a_ih[2][0], xA, bias[2], 0, 0, 0);
    f32x4 ao = __builtin_amdgcn_mfma_f32_16x16x32_bf16(a_ih[3][0], xA, bias[3], 0, 0, 0);
    ai = __builtin_amdgcn_mfma_f32_16x16x32_bf16(a_ih[0][1], xB, ai, 0, 0, 0);
    af = __builtin_amdgcn_mfma_f32_16x16x32_bf16(a_ih[1][1], xB, af, 0, 0, 0);
    ag = __builtin_amdgcn_mfma_f32_16x16x32_bf16(a_ih[2][1], xB, ag, 0, 0, 0);
    ao = __builtin_amdgcn_mfma_f32_16x16x32_bf16(a_ih[3][1], xB, ao, 0, 0, 0);
    // dependent h-part: B[k=unit q*8+j][n=row m] from LDS (contiguous -> ds_read_b128)
    const bf16x8 hfr = *(const bf16x8*)(&hbuf[pb][m * HSTR + (q << 3)]);
    ai = __builtin_amdgcn_mfma_f32_16x16x32_bf16(a_hh[0], hfr, ai, 0, 0, 0);
    af = __builtin_amdgcn_mfma_f32_16x16x32_bf16(a_hh[1], hfr, af, 0, 0, 0);
    ag = __builtin_amdgcn_mfma_f32_16x16x32_bf16(a_hh[2], hfr, ag, 0, 0, 0);
    ao = __builtin_amdgcn_mfma_f32_16x16x32_bf16(a_hh[3], hfr, ao, 0, 0, 0);
    // elementwise: 4 cells/lane (units u0+4q+r, row m)
    bf16x4 hv;
    #pragma unroll
    for (int r = 0; r < 4; ++r) {
      const float ig = fast_sigmoid(ai[r]);
      const float fg = fast_sigmoid(af[r]);
      const float gg = fast_tanh(ag[r]);
      const float og = fast_sigmoid(ao[r]);
      const float cn = fg * cst[r] + ig * gg;
      cst[r] = cn;
      const float h = og * fast_tanh(cn);
      hv[r] = (bf16_t)h;
      if (t == T_STEPS - 1) hf[m * FSTR + u0 + (q << 2) + r] = fmaxf(h, 0.0f);
    }
    // contiguous 4-unit write -> ds_write_b64 (8B-aligned: 80m + 2u0 + 8q)
    *(bf16x4*)(&hbuf[pb ^ 1][m * HSTR + u0 + (q << 2)]) = hv;
    barrier_lgkm();
  }

  __syncthreads();

  // dense epilogue: out[row][a] = relu(h_T[row]) . W_d[a] + b_d[a]   (fp32 out)
  if (tid < 48) {
    const int r = tid / 3;
    const int a = tid - r * 3;
    float s = b_d[a];
    #pragma unroll
    for (int u = 0; u < HID; ++u)
      s += hf[r * FSTR + u] * W_d[a * HID + u];
    out[(size_t)(row0 + r) * 3 + a] = s;
  }
}

extern "C" void kernel_launch(void* const* d_in, const int* in_sizes, int n_in,
                              void* d_out, int out_size, void* d_ws, size_t ws_size,
                              hipStream_t stream) {
  const float* x    = (const float*)d_in[0];
  const float* W_ih = (const float*)d_in[1];
  const float* W_hh = (const float*)d_in[2];
  const float* b_ih = (const float*)d_in[3];
  const float* b_hh = (const float*)d_in[4];
  const float* W_d  = (const float*)d_in[5];
  const float* b_d  = (const float*)d_in[6];
  float* out = (float*)d_out;

  dim3 grid(BATCH / 16);   // 128 blocks x 16 batch rows
  dim3 block(128);         // 2 waves: unit-tiles [0,16) and [16,31)
  hipLaunchKernelGGL(lstm_policy_kernel, grid, block, 0, stream,
                     x, W_ih, W_hh, b_ih, b_hh, W_d, b_d, out);
}

// Round 4
// 504.571 us; speedup vs baseline: 1.1360x; 1.0707x over previous
//
#include <hip/hip_runtime.h>

typedef __bf16 bf16_t;
typedef __bf16 bf16x8 __attribute__((ext_vector_type(8)));
typedef __bf16 bf16x4 __attribute__((ext_vector_type(4)));
typedef float  f32x4  __attribute__((ext_vector_type(4)));

#define T_STEPS 512
#define BATCH   2048
#define NS      64
#define HID     32
#define HSTR    40   // bf16 elems per LDS h row: <=2-way bank alias (free per m136)
#define FSTR    36   // f32 elems per LDS final-h row

__device__ __forceinline__ float fast_sigmoid(float x) {
  return __builtin_amdgcn_rcpf(1.0f + __builtin_amdgcn_exp2f(-1.4426950408889634f * x));
}
__device__ __forceinline__ float fast_tanh(float x) {
  return 1.0f - 2.0f * __builtin_amdgcn_rcpf(1.0f + __builtin_amdgcn_exp2f(2.8853900817779268f * x));
}

// lgkm-only barrier: global x-prefetch loads stay in flight across it
__device__ __forceinline__ void barrier_lgkm() {
  asm volatile("s_waitcnt lgkmcnt(0)\n\ts_barrier" ::: "memory");
}

#define MFMA(A, B, C) __builtin_amdgcn_mfma_f32_16x16x32_bf16((A), (B), (C), 0, 0, 0)

__global__ __launch_bounds__(128, 1)
void lstm_policy_kernel(const float* __restrict__ x,
                        const float* __restrict__ W_ih,
                        const float* __restrict__ W_hh,
                        const float* __restrict__ b_ih,
                        const float* __restrict__ b_hh,
                        const float* __restrict__ W_d,
                        const float* __restrict__ b_d,
                        float* __restrict__ out)
{
  __shared__ bf16_t hbuf[2][16 * HSTR];   // double-buffered h (bf16), [row][unit]
  __shared__ float  hf[16 * FSTR];        // final relu(h) f32 for dense epilogue

  const int tid  = threadIdx.x;
  const int wave = tid >> 6;              // 0..1 : unit-tile
  const int lane = tid & 63;
  const int m    = lane & 15;             // batch row within tile
  const int q    = lane >> 4;             // 0..3
  const int u0   = wave << 4;             // unit base for this wave's gate tiles
  const int row0 = blockIdx.x << 4;       // global batch row base

  // zero h_{-1}
  for (int i = tid; i < 16 * HSTR; i += 128) hbuf[0][i] = (bf16_t)0.0f;

  // ---- preload + convert weight A-frags (A[m=unit_local][k], lane: unit=m, k=q*8+j) ----
  bf16x8 a_ih[4][2], a_hh[4];
  f32x4  bias[4];
  #pragma unroll
  for (int G = 0; G < 4; ++G) {
    const int wrow = (G << 5) + u0 + m;     // row of W_ih/W_hh (gate-major, 4H=128 rows)
    const float* pih = W_ih + wrow * 64;
    const float* phh = W_hh + (wrow << 5);
    #pragma unroll
    for (int j = 0; j < 8; ++j) {
      a_ih[G][0][j] = (bf16_t)pih[(q << 3) + j];
      a_ih[G][1][j] = (bf16_t)pih[32 + (q << 3) + j];
      a_hh[G][j]    = (bf16_t)phh[(q << 3) + j];
    }
    #pragma unroll
    for (int r = 0; r < 4; ++r) {
      const int u = (G << 5) + u0 + (q << 2) + r;  // C-cell gate-row for acc reg r
      bias[G][r] = b_ih[u] + b_hh[u];
    }
  }

  const size_t xstep = (size_t)BATCH * NS;
  const float* xr = x + (size_t)(row0 + m) * NS + (q << 3);

  // ---- x ring: slot s holds x[t] with t%4==s (after prologue: s0=x[4], s1=x[1], s2=x[2], s3=x[3]) ----
  f32x4 xf[4][4];
  {
    const float* p1 = xr + xstep;
    const float* p2 = xr + 2 * xstep;
    const float* p3 = xr + 3 * xstep;
    const float* p4 = xr + 4 * xstep;
    xf[1][0]=*(const f32x4*)(p1); xf[1][1]=*(const f32x4*)(p1+4); xf[1][2]=*(const f32x4*)(p1+32); xf[1][3]=*(const f32x4*)(p1+36);
    xf[2][0]=*(const f32x4*)(p2); xf[2][1]=*(const f32x4*)(p2+4); xf[2][2]=*(const f32x4*)(p2+32); xf[2][3]=*(const f32x4*)(p2+36);
    xf[3][0]=*(const f32x4*)(p3); xf[3][1]=*(const f32x4*)(p3+4); xf[3][2]=*(const f32x4*)(p3+32); xf[3][3]=*(const f32x4*)(p3+36);
    xf[0][0]=*(const f32x4*)(p4); xf[0][1]=*(const f32x4*)(p4+4); xf[0][2]=*(const f32x4*)(p4+32); xf[0][3]=*(const f32x4*)(p4+36);
  }

  // ---- acc[2][4]: gate pre-activations (x-part + bias), software-pipelined one step ahead ----
  f32x4 acc[2][4];
  {
    // x[0] for step 0 -> acc[0]
    f32x4 x0a = *(const f32x4*)(xr), x0b = *(const f32x4*)(xr + 4);
    f32x4 x0c = *(const f32x4*)(xr + 32), x0d = *(const f32x4*)(xr + 36);
    bf16x8 xA, xB;
    #pragma unroll
    for (int j = 0; j < 4; ++j) {
      xA[j] = (bf16_t)x0a[j]; xA[4+j] = (bf16_t)x0b[j];
      xB[j] = (bf16_t)x0c[j]; xB[4+j] = (bf16_t)x0d[j];
    }
    #pragma unroll
    for (int G = 0; G < 4; ++G) {
      acc[0][G] = MFMA(a_ih[G][0], xA, bias[G]);
      acc[0][G] = MFMA(a_ih[G][1], xB, acc[0][G]);
    }
  }

  float cst[4] = {0.0f, 0.0f, 0.0f, 0.0f};  // c-state: units u0+4q+r, row m — lane-resident

  __syncthreads();

  // STEP(P): phase P of a 4-step group at base t.
  // Critical path: ds_read h -> 1 h-MFMA -> elem. x-path for t+1 fills the ds_read latency.
  #define STEP(P)                                                                     \
  do {                                                                                \
    const int tt = t + (P);                                                           \
    /* h(t-1) frag: issue first, consume after x-block */                             \
    const bf16x8 hfr = *(const bf16x8*)(&hbuf[(P) & 1][m * HSTR + (q << 3)]);         \
    /* x pipeline: gates x-part for t+1 into acc[(P+1)&1], then reload slot */        \
    {                                                                                 \
      bf16x8 xA, xB;                                                                  \
      _Pragma("unroll")                                                               \
      for (int j = 0; j < 4; ++j) {                                                   \
        xA[j]   = (bf16_t)xf[((P)+1)&3][0][j]; xA[4+j] = (bf16_t)xf[((P)+1)&3][1][j]; \
        xB[j]   = (bf16_t)xf[((P)+1)&3][2][j]; xB[4+j] = (bf16_t)xf[((P)+1)&3][3][j]; \
      }                                                                               \
      _Pragma("unroll")                                                               \
      for (int G = 0; G < 4; ++G) {                                                   \
        acc[((P)+1)&1][G] = MFMA(a_ih[G][0], xA, bias[G]);                            \
        acc[((P)+1)&1][G] = MFMA(a_ih[G][1], xB, acc[((P)+1)&1][G]);                  \
      }                                                                               \
      int tp = tt + 5; if (tp > T_STEPS - 1) tp = T_STEPS - 1;                        \
      const float* pf = xr + (size_t)tp * xstep;                                      \
      xf[((P)+1)&3][0] = *(const f32x4*)(pf);                                         \
      xf[((P)+1)&3][1] = *(const f32x4*)(pf + 4);                                     \
      xf[((P)+1)&3][2] = *(const f32x4*)(pf + 32);                                    \
      xf[((P)+1)&3][3] = *(const f32x4*)(pf + 36);                                    \
    }                                                                                 \
    /* h-part: single MFMA per gate on the critical path */                           \
    f32x4 gi = MFMA(a_hh[0], hfr, acc[(P)&1][0]);                                     \
    f32x4 gf = MFMA(a_hh[1], hfr, acc[(P)&1][1]);                                     \
    f32x4 gg = MFMA(a_hh[2], hfr, acc[(P)&1][2]);                                     \
    f32x4 go = MFMA(a_hh[3], hfr, acc[(P)&1][3]);                                     \
    bf16x4 hv;                                                                        \
    _Pragma("unroll")                                                                 \
    for (int r = 0; r < 4; ++r) {                                                     \
      const float ig = fast_sigmoid(gi[r]);                                           \
      const float fg = fast_sigmoid(gf[r]);                                           \
      const float gv = fast_tanh(gg[r]);                                              \
      const float og = fast_sigmoid(go[r]);                                           \
      const float cn = fg * cst[r] + ig * gv;                                         \
      cst[r] = cn;                                                                    \
      const float h = og * fast_tanh(cn);                                             \
      hv[r] = (bf16_t)h;                                                              \
      if (tt == T_STEPS - 1) hf[m * FSTR + u0 + (q << 2) + r] = fmaxf(h, 0.0f);       \
    }                                                                                 \
    *(bf16x4*)(&hbuf[((P)&1)^1][m * HSTR + u0 + (q << 2)]) = hv;                      \
    barrier_lgkm();                                                                   \
  } while (0)

  #pragma unroll 1
  for (int t = 0; t < T_STEPS; t += 4) {
    STEP(0);
    STEP(1);
    STEP(2);
    STEP(3);
  }
  #undef STEP

  __syncthreads();

  // dense epilogue: out[row][a] = relu(h_T[row]) . W_d[a] + b_d[a]   (fp32 out)
  if (tid < 48) {
    const int r = tid / 3;
    const int a = tid - r * 3;
    float s = b_d[a];
    #pragma unroll
    for (int u = 0; u < HID; ++u)
      s += hf[r * FSTR + u] * W_d[a * HID + u];
    out[(size_t)(row0 + r) * 3 + a] = s;
  }
}

extern "C" void kernel_launch(void* const* d_in, const int* in_sizes, int n_in,
                              void* d_out, int out_size, void* d_ws, size_t ws_size,
                              hipStream_t stream) {
  const float* x    = (const float*)d_in[0];
  const float* W_ih = (const float*)d_in[1];
  const float* W_hh = (const float*)d_in[2];
  const float* b_ih = (const float*)d_in[3];
  const float* b_hh = (const float*)d_in[4];
  const float* W_d  = (const float*)d_in[5];
  const float* b_d  = (const float*)d_in[6];
  float* out = (float*)d_out;

  dim3 grid(BATCH / 16);   // 128 blocks x 16 batch rows
  dim3 block(128);         // 2 waves: unit-tiles [0,16) and [16,32)
  hipLaunchKernelGGL(lstm_policy_kernel, grid, block, 0, stream,
                     x, W_ih, W_hh, b_ih, b_hh, W_d, b_d, out);
}